// Round 1
// baseline (179.773 us; speedup 1.0000x reference)
//
#include <hip/hip_runtime.h>
#include <hip/hip_bf16.h>
#include <cstdint>

// Problem constants: T=512 timesteps/slots, B=64 batch, E=512 embed.
#define TT 512
#define BB 64
#define EE 512

typedef short bf16x8 __attribute__((ext_vector_type(8)));   // 8 bf16 = 4 VGPRs (A/B frag)
typedef float f32x4  __attribute__((ext_vector_type(4)));   // C/D frag

static __device__ __forceinline__ unsigned short f32_to_bf16(float f) {
    unsigned u = __float_as_uint(f);
    u += 0x7fffu + ((u >> 16) & 1u);   // RNE; values are finite, no NaN handling needed
    return (unsigned short)(u >> 16);
}

// ---------------------------------------------------------------------------
// K1: queue strength recurrence via prefix-sum trick.
//   P_i(t): P <- relu(P - u_t); if (t<=i) P += d_t
//   C[t,i,b] = min(P_i,1) - min(P_{i-1},1)
// One thread per (b, i); each thread also runs the P_{i-1} recurrence.
// Grid: 64*4 blocks x 128 threads.
// ---------------------------------------------------------------------------
__global__ __launch_bounds__(128) void queue_coeffs_kernel(
        const float* __restrict__ U, const float* __restrict__ D,
        unsigned short* __restrict__ C) {
    const int b     = blockIdx.x >> 2;
    const int chunk = blockIdx.x & 3;
    const int i     = chunk * 128 + threadIdx.x;

    __shared__ float Us[TT];
    __shared__ float Ds[TT];
    for (int t = threadIdx.x; t < TT; t += 128) {
        Us[t] = U[t * BB + b];
        Ds[t] = D[t * BB + b];
    }
    __syncthreads();

    float P = 0.f, Pm = 0.f;
    unsigned short* Crow = C + (size_t)b * TT * TT + i;
    #pragma unroll 8
    for (int t = 0; t < TT; ++t) {
        const float u = Us[t];
        const float d = Ds[t];
        P  = fmaxf(P  - u, 0.f);
        Pm = fmaxf(Pm - u, 0.f);
        if (t <= i) P  += d;   // push lands in slot t
        if (t <  i) Pm += d;
        const float c = fminf(P, 1.f) - fminf(Pm, 1.f);
        Crow[(size_t)t * TT] = f32_to_bf16(c);
    }
}

// ---------------------------------------------------------------------------
// K2: V[i,b,e] fp32  ->  VbT[b][e][i] bf16 (transpose-convert, LDS tiled).
// Grid: dim3(E/64, T/64, B) x 256 threads.
// ---------------------------------------------------------------------------
__global__ __launch_bounds__(256) void transpose_v_kernel(
        const float* __restrict__ V, unsigned short* __restrict__ Vt) {
    __shared__ unsigned short tile[64][65];
    const int b  = blockIdx.z;
    const int i0 = blockIdx.y * 64;
    const int e0 = blockIdx.x * 64;
    const int tx = threadIdx.x & 63;
    const int ty = threadIdx.x >> 6;

    #pragma unroll
    for (int r = 0; r < 16; ++r) {
        const int il = r * 4 + ty;
        tile[il][tx] = f32_to_bf16(V[((size_t)(i0 + il) * BB + b) * EE + e0 + tx]);
    }
    __syncthreads();
    #pragma unroll
    for (int r = 0; r < 16; ++r) {
        const int el = r * 4 + ty;
        Vt[((size_t)b * EE + e0 + el) * TT + i0 + tx] = tile[tx][el];
    }
}

// ---------------------------------------------------------------------------
// K3: batched NT GEMM, R_b[t,e] = sum_i C_b[t,i] * VbT_b[e,i], bf16 MFMA.
// 128x128 tile, BK=32, global_load_lds width-16 staging (m97 structure).
// Grid: dim3(4,4,64) x 256 threads (4 waves, each a 64x64 output quadrant).
// ---------------------------------------------------------------------------
static __device__ __forceinline__ void gl2lds16(const unsigned short* g,
                                                const unsigned short* l) {
    __builtin_amdgcn_global_load_lds(
        (const __attribute__((address_space(1))) unsigned int*)(uintptr_t)g,
        (__attribute__((address_space(3))) unsigned int*)(unsigned int)(uintptr_t)l,
        16, 0, 0);
}

__global__ __launch_bounds__(256) void gemm_nt_kernel(
        const unsigned short* __restrict__ A,   // [B][T][T]  C_ws (m=t, k=i)
        const unsigned short* __restrict__ Bt,  // [B][E][T]  VbT  (n=e, k=i)
        float* __restrict__ out) {              // [T][B][E]
    const int b  = blockIdx.z;
    const int m0 = blockIdx.x * 128;
    const int n0 = blockIdx.y * 128;
    const unsigned short* Ab = A  + (size_t)b * TT * TT;
    const unsigned short* Bb = Bt + (size_t)b * EE * TT;

    __shared__ __align__(16) unsigned short As[128 * 32];
    __shared__ __align__(16) unsigned short Bs[128 * 32];

    const int tid  = threadIdx.x;
    const int wave = tid >> 6;
    const int lane = tid & 63;
    const int lrow = lane >> 2;          // staging row within 16-row wave slab
    const int lcol = (lane & 3) * 8;     // staging col (elements)
    const int m_off = (wave >> 1) * 64;
    const int n_off = (wave & 1) * 64;
    const int frow = lane & 15;          // fragment row (m or n)
    const int quad = lane >> 4;          // fragment k-quad

    f32x4 acc[4][4];
    #pragma unroll
    for (int mi = 0; mi < 4; ++mi)
        #pragma unroll
        for (int ni = 0; ni < 4; ++ni)
            acc[mi][ni] = f32x4{0.f, 0.f, 0.f, 0.f};

    for (int k0 = 0; k0 < TT; k0 += 32) {
        #pragma unroll
        for (int p = 0; p < 2; ++p) {
            const int r = p * 64 + wave * 16 + lrow;
            const unsigned short* ldst = As + (p * 64 + wave * 16) * 32; // +lane*8 implicit
            gl2lds16(Ab + (size_t)(m0 + r) * TT + k0 + lcol, ldst);
            const unsigned short* ldstB = Bs + (p * 64 + wave * 16) * 32;
            gl2lds16(Bb + (size_t)(n0 + r) * TT + k0 + lcol, ldstB);
        }
        __syncthreads();

        bf16x8 af[4], bfr[4];
        #pragma unroll
        for (int mi = 0; mi < 4; ++mi)
            af[mi] = *(const bf16x8*)(As + (m_off + mi * 16 + frow) * 32 + quad * 8);
        #pragma unroll
        for (int ni = 0; ni < 4; ++ni)
            bfr[ni] = *(const bf16x8*)(Bs + (n_off + ni * 16 + frow) * 32 + quad * 8);

        #pragma unroll
        for (int mi = 0; mi < 4; ++mi)
            #pragma unroll
            for (int ni = 0; ni < 4; ++ni)
                acc[mi][ni] = __builtin_amdgcn_mfma_f32_16x16x32_bf16(
                    af[mi], bfr[ni], acc[mi][ni], 0, 0, 0);
        __syncthreads();
    }

    // Epilogue: C/D layout col=lane&15, row=quad*4+r (m89/m91 verified).
    #pragma unroll
    for (int mi = 0; mi < 4; ++mi) {
        #pragma unroll
        for (int r = 0; r < 4; ++r) {
            const int t = m0 + m_off + mi * 16 + quad * 4 + r;
            float* orow = out + ((size_t)t * BB + b) * EE + n0 + n_off + frow;
            #pragma unroll
            for (int ni = 0; ni < 4; ++ni)
                orow[ni * 16] = acc[mi][ni][r];
        }
    }
}

extern "C" void kernel_launch(void* const* d_in, const int* in_sizes, int n_in,
                              void* d_out, int out_size, void* d_ws, size_t ws_size,
                              hipStream_t stream) {
    const float* V = (const float*)d_in[0];   // [T,B,E]
    const float* U = (const float*)d_in[1];   // [T,B]
    const float* D = (const float*)d_in[2];   // [T,B]
    float* out = (float*)d_out;               // [T,B,E]

    unsigned short* C_ws = (unsigned short*)d_ws;                    // [B][T][T] bf16, 32 MB
    unsigned short* VbT  = C_ws + (size_t)BB * TT * TT;              // [B][E][T] bf16, 32 MB

    queue_coeffs_kernel<<<dim3(BB * 4), dim3(128), 0, stream>>>(U, D, C_ws);
    transpose_v_kernel<<<dim3(EE / 64, TT / 64, BB), dim3(256), 0, stream>>>(V, VbT);
    gemm_nt_kernel<<<dim3(4, 4, BB), dim3(256), 0, stream>>>(C_ws, VbT, out);
}